// Round 1
// baseline (1940.998 us; speedup 1.0000x reference)
//
#include <hip/hip_runtime.h>

#define BATCH 2
#define NPART 32768
#define GD 64
#define NVOX (BATCH * GD * GD * GD)   // 524288

__device__ __forceinline__ float poly6_c() {
    const double H9 = 1.0 / 35184372088832.0; // 0.03125^9 == 2^-45 (exact)
    return (float)(315.0 / (64.0 * 3.14159265358979323846 * H9));
}

// ---------------- zero the 4-channel splat grid ----------------
__global__ void zero_kernel(float4* __restrict__ p, int n4) {
    int t = blockIdx.x * blockDim.x + threadIdx.x;
    if (t < n4) p[t] = float4{0.f, 0.f, 0.f, 0.f};
}

// ---------------- weight repack: W[O][I][27] -> Wr[I*27][O] ----------------
__global__ void repack_kernel(const float* __restrict__ W, float* __restrict__ Wr,
                              int O, int I) {
    int t = blockIdx.x * blockDim.x + threadIdx.x;
    int total = O * I * 27;
    if (t >= total) return;
    int o = t / (I * 27);
    int rem = t - o * (I * 27);      // i*27 + tap
    Wr[rem * O + o] = W[t];
}

// ---------------- particles2grid (poly6 scatter) ----------------
__global__ __launch_bounds__(256) void splat_kernel(
    const float* __restrict__ locs, const float* __restrict__ data,
    const float* __restrict__ density, float* __restrict__ grid) {
    int t = blockIdx.x * blockDim.x + threadIdx.x;     // B*N threads
    if (t >= BATCH * NPART) return;
    int b = t >> 15;                                   // N = 32768

    float px = locs[t * 3 + 0];
    float py = locs[t * 3 + 1];
    float pz = locs[t * 3 + 2];
    float inv_d = 1.0f / density[t];
    float v0 = data[t * 4 + 0] * inv_d;
    float v1 = data[t * 4 + 1] * inv_d;
    float v2 = data[t * 4 + 2] * inv_d;
    float v3 = data[t * 4 + 3] * inv_d;

    int bx = (int)floorf(px * 64.0f);
    int by = (int)floorf(py * 64.0f);
    int bz = (int)floorf(pz * 64.0f);

    const float step = 0.015625f;
    const float h2 = 0.03125f * 0.03125f;
    const float cc = poly6_c();

    float* gb = grid + (size_t)b * GD * GD * GD * 4;

    for (int dx = -2; dx <= 2; ++dx) {
        int x = bx + dx;
        if ((unsigned)x > 63u) continue;
        float cx = ((float)x + 0.5f) * step - px;
        float dx2 = cx * cx;
        for (int dy = -2; dy <= 2; ++dy) {
            int y = by + dy;
            if ((unsigned)y > 63u) continue;
            float cy = ((float)y + 0.5f) * step - py;
            float dxy2 = dx2 + cy * cy;
            if (dxy2 > h2) continue;
            for (int dz = -2; dz <= 2; ++dz) {
                int z = bz + dz;
                if ((unsigned)z > 63u) continue;
                float cz = ((float)z + 0.5f) * step - pz;
                float d2 = dxy2 + cz * cz;
                if (d2 > h2) continue;
                float u = h2 - d2;
                float w = cc * u * u * u;
                float* gp = gb + (size_t)(((x * GD) + y) * GD + z) * 4;
                atomicAdd(gp + 0, w * v0);
                atomicAdd(gp + 1, w * v1);
                atomicAdd(gp + 2, w * v2);
                atomicAdd(gp + 3, w * v3);
            }
        }
    }
}

// ---------------- direct 3x3x3 conv, channels-last ----------------
// in:  [B,64,64,64,CIN], Wr: [CIN*27][COUT], out: [B,64,64,64,COUT]
template <int CIN, int COUT, bool HAS_PRELU>
__global__ __launch_bounds__(256) void conv3d_kernel(
    const float* __restrict__ in, const float* __restrict__ Wr,
    const float* __restrict__ bias, const float* __restrict__ alpha,
    float* __restrict__ out) {
    int idx = blockIdx.x * 256 + threadIdx.x;          // NVOX threads exactly
    int z = idx & 63;
    int y = (idx >> 6) & 63;
    int x = (idx >> 12) & 63;
    int b = idx >> 18;
    const float* inb = in + (size_t)b * GD * GD * GD * CIN;

    float acc[COUT];
#pragma unroll
    for (int o = 0; o < COUT; ++o) acc[o] = bias[o];

#pragma unroll 1
    for (int kd = 0; kd < 3; ++kd) {
        int xx = x + kd - 1;
        if ((unsigned)xx > 63u) continue;              // wave-uniform
#pragma unroll 1
        for (int kh = 0; kh < 3; ++kh) {
            int yy = y + kh - 1;
            if ((unsigned)yy > 63u) continue;          // wave-uniform
#pragma unroll 1
            for (int kw = 0; kw < 3; ++kw) {
                int zz = z + kw - 1;
                if ((unsigned)zz > 63u) continue;      // diverges on 2/64 lanes only
                const float* ip = inb + (size_t)(((xx * GD) + yy) * GD + zz) * CIN;
                int tap = (kd * 3 + kh) * 3 + kw;

                float inv[CIN];
#pragma unroll
                for (int i4 = 0; i4 < CIN; i4 += 4) {
                    const float4 v = *(const float4*)(ip + i4);
                    inv[i4 + 0] = v.x;
                    inv[i4 + 1] = v.y;
                    inv[i4 + 2] = v.z;
                    inv[i4 + 3] = v.w;
                }
#pragma unroll
                for (int i = 0; i < CIN; ++i) {
                    const float* wp = Wr + (i * 27 + tap) * COUT;  // wave-uniform addr
                    float v = inv[i];
#pragma unroll
                    for (int o = 0; o < COUT; ++o)
                        acc[o] = fmaf(v, wp[o], acc[o]);
                }
            }
        }
    }

    float* op = out + (size_t)idx * COUT;
    if (HAS_PRELU) {
        float a = alpha[0];
#pragma unroll
        for (int o = 0; o < COUT; ++o) {
            float v = acc[o];
            op[o] = (v >= 0.f) ? v : a * v;
        }
    } else {
#pragma unroll
        for (int o = 0; o < COUT; ++o) op[o] = acc[o];
    }
}

// ---------------- grid2particles (trilinear gather) ----------------
__global__ __launch_bounds__(256) void gather_kernel(
    const float* __restrict__ grid, const float* __restrict__ locs,
    float* __restrict__ out) {
    int t = blockIdx.x * blockDim.x + threadIdx.x;
    if (t >= BATCH * NPART) return;
    int b = t >> 15;

    float px = locs[t * 3 + 0] * 64.0f - 0.5f;
    float py = locs[t * 3 + 1] * 64.0f - 0.5f;
    float pz = locs[t * 3 + 2] * 64.0f - 0.5f;
    int ix = (int)floorf(px);
    int iy = (int)floorf(py);
    int iz = (int)floorf(pz);
    float fx = px - (float)ix;
    float fy = py - (float)iy;
    float fz = pz - (float)iz;

    const float* gb = grid + (size_t)b * GD * GD * GD * 4;
    float o0 = 0.f, o1 = 0.f, o2 = 0.f, o3 = 0.f;

#pragma unroll
    for (int dx = 0; dx < 2; ++dx) {
        int x = ix + dx;
        if ((unsigned)x > 63u) continue;
        float wx = dx ? fx : 1.0f - fx;
#pragma unroll
        for (int dy = 0; dy < 2; ++dy) {
            int y = iy + dy;
            if ((unsigned)y > 63u) continue;
            float wy = dy ? fy : 1.0f - fy;
#pragma unroll
            for (int dz = 0; dz < 2; ++dz) {
                int z = iz + dz;
                if ((unsigned)z > 63u) continue;
                float wz = dz ? fz : 1.0f - fz;
                float w = wx * wy * wz;
                const float4 g = *(const float4*)(gb + (size_t)(((x * GD) + y) * GD + z) * 4);
                o0 += w * g.x;
                o1 += w * g.y;
                o2 += w * g.z;
                o3 += w * g.w;
            }
        }
    }
    out[t * 4 + 0] = o0;
    out[t * 4 + 1] = o1;
    out[t * 4 + 2] = o2;
    out[t * 4 + 3] = o3;
}

extern "C" void kernel_launch(void* const* d_in, const int* in_sizes, int n_in,
                              void* d_out, int out_size, void* d_ws, size_t ws_size,
                              hipStream_t stream) {
    const float* locs    = (const float*)d_in[0];
    const float* data    = (const float*)d_in[1];
    const float* density = (const float*)d_in[2];
    const float* W0 = (const float*)d_in[3];
    const float* b0 = (const float*)d_in[4];
    const float* W1 = (const float*)d_in[5];
    const float* b1 = (const float*)d_in[6];
    const float* W2 = (const float*)d_in[7];
    const float* b2 = (const float*)d_in[8];
    const float* W3 = (const float*)d_in[9];
    const float* b3 = (const float*)d_in[10];
    const float* a0 = (const float*)d_in[11];
    const float* a1 = (const float*)d_in[12];
    const float* a2 = (const float*)d_in[13];
    float* out = (float*)d_out;

    char* ws = (char*)d_ws;
    // layout: g4 (8 MB) | gA (64 MB) | gB (64 MB) | repacked weights
    float* g4  = (float*)(ws);
    float* gA  = (float*)(ws + 8388608);
    float* gB  = (float*)(ws + 8388608 + 67108864);
    float* w0r = (float*)(ws + 8388608 + 2 * 67108864);
    float* w1r = w0r + 32 * 4 * 27;
    float* w2r = w1r + 32 * 32 * 27;
    float* w3r = w2r + 32 * 32 * 27;

    // zero the splat grid (ws is poisoned 0xAA before every call)
    zero_kernel<<<NVOX / 256, 256, 0, stream>>>((float4*)g4, NVOX);  // NVOX float4 == B*64^3*4 floats

    // repack weights to [ic*27][oc]
    repack_kernel<<<(32 * 4 * 27 + 255) / 256, 256, 0, stream>>>(W0, w0r, 32, 4);
    repack_kernel<<<(32 * 32 * 27 + 255) / 256, 256, 0, stream>>>(W1, w1r, 32, 32);
    repack_kernel<<<(32 * 32 * 27 + 255) / 256, 256, 0, stream>>>(W2, w2r, 32, 32);
    repack_kernel<<<(4 * 32 * 27 + 255) / 256, 256, 0, stream>>>(W3, w3r, 4, 32);

    // particles -> grid
    splat_kernel<<<(BATCH * NPART) / 256, 256, 0, stream>>>(locs, data, density, g4);

    // conv chain (channels-last)
    conv3d_kernel<4, 32, true><<<NVOX / 256, 256, 0, stream>>>(g4, w0r, b0, a0, gA);
    conv3d_kernel<32, 32, true><<<NVOX / 256, 256, 0, stream>>>(gA, w1r, b1, a1, gB);
    conv3d_kernel<32, 32, true><<<NVOX / 256, 256, 0, stream>>>(gB, w2r, b2, a2, gA);
    conv3d_kernel<32, 4, false><<<NVOX / 256, 256, 0, stream>>>(gA, w3r, b3, b3, gB);

    // grid -> particles
    gather_kernel<<<(BATCH * NPART) / 256, 256, 0, stream>>>(gB, locs, out);
}

// Round 2
// 704.546 us; speedup vs baseline: 2.7550x; 2.7550x over previous
//
#include <hip/hip_runtime.h>

#define BATCH 2
#define NPART 32768
#define GD 64
#define NVOX (BATCH * GD * GD * GD)   // 524288

typedef unsigned short ushortT;
typedef __attribute__((ext_vector_type(8))) short short8;
typedef __attribute__((ext_vector_type(16))) float float16;

__device__ __forceinline__ float poly6_c() {
    const double H9 = 1.0 / 35184372088832.0; // 0.03125^9 == 2^-45 (exact)
    return (float)(315.0 / (64.0 * 3.14159265358979323846 * H9));
}

__device__ __forceinline__ ushortT bf16_rne(float f) {
    unsigned int u = __float_as_uint(f);
    u = (u + 0x7fffu + ((u >> 16) & 1u)) >> 16;   // round-to-nearest-even
    return (ushortT)u;
}

// ---------------- zero the 4-channel splat grid ----------------
__global__ void zero_kernel(float4* __restrict__ p, int n4) {
    int t = blockIdx.x * blockDim.x + threadIdx.x;
    if (t < n4) p[t] = float4{0.f, 0.f, 0.f, 0.f};
}

// ---------------- particles2grid (poly6 scatter, fp32) ----------------
__global__ __launch_bounds__(256) void splat_kernel(
    const float* __restrict__ locs, const float* __restrict__ data,
    const float* __restrict__ density, float* __restrict__ grid) {
    int t = blockIdx.x * blockDim.x + threadIdx.x;
    if (t >= BATCH * NPART) return;
    int b = t >> 15;

    float px = locs[t * 3 + 0];
    float py = locs[t * 3 + 1];
    float pz = locs[t * 3 + 2];
    float inv_d = 1.0f / density[t];
    float v0 = data[t * 4 + 0] * inv_d;
    float v1 = data[t * 4 + 1] * inv_d;
    float v2 = data[t * 4 + 2] * inv_d;
    float v3 = data[t * 4 + 3] * inv_d;

    int bx = (int)floorf(px * 64.0f);
    int by = (int)floorf(py * 64.0f);
    int bz = (int)floorf(pz * 64.0f);

    const float step = 0.015625f;
    const float h2 = 0.03125f * 0.03125f;
    const float cc = poly6_c();

    float* gb = grid + (size_t)b * GD * GD * GD * 4;

    for (int dx = -2; dx <= 2; ++dx) {
        int x = bx + dx;
        if ((unsigned)x > 63u) continue;
        float cx = ((float)x + 0.5f) * step - px;
        float dx2 = cx * cx;
        for (int dy = -2; dy <= 2; ++dy) {
            int y = by + dy;
            if ((unsigned)y > 63u) continue;
            float cy = ((float)y + 0.5f) * step - py;
            float dxy2 = dx2 + cy * cy;
            if (dxy2 > h2) continue;
            for (int dz = -2; dz <= 2; ++dz) {
                int z = bz + dz;
                if ((unsigned)z > 63u) continue;
                float cz = ((float)z + 0.5f) * step - pz;
                float d2 = dxy2 + cz * cz;
                if (d2 > h2) continue;
                float u = h2 - d2;
                float w = cc * u * u * u;
                float* gp = gb + (size_t)(((x * GD) + y) * GD + z) * 4;
                atomicAdd(gp + 0, w * v0);
                atomicAdd(gp + 1, w * v1);
                atomicAdd(gp + 2, w * v2);
                atomicAdd(gp + 3, w * v3);
            }
        }
    }
}

// ---------------- fp32 4ch grid -> bf16 8ch grid (ch 4..7 = 0) ----------------
__global__ __launch_bounds__(256) void convert_kernel(
    const float4* __restrict__ g4, short8* __restrict__ g8) {
    int t = blockIdx.x * blockDim.x + threadIdx.x;   // NVOX
    float4 v = g4[t];
    short8 o;
    o[0] = (short)bf16_rne(v.x);
    o[1] = (short)bf16_rne(v.y);
    o[2] = (short)bf16_rne(v.z);
    o[3] = (short)bf16_rne(v.w);
    o[4] = 0; o[5] = 0; o[6] = 0; o[7] = 0;
    g8[t] = o;
}

// ---------------- weight repack into MFMA B-fragment order ----------------
// Bpack[kt][lane][j] (bf16), lane: n = l&31, q = l>>5; k = kt*16 + 8q + j
// k = tap*CINP + ic ; valid iff tap<27 && ic<I && n<O
__global__ void repack_kernel(const float* __restrict__ W, short* __restrict__ Bp,
                              int O, int I, int CINP, int KT) {
    int t = blockIdx.x * blockDim.x + threadIdx.x;
    int total = KT * 512;
    if (t >= total) return;
    int kt = t >> 9;
    int l  = (t >> 3) & 63;
    int j  = t & 7;
    int n = l & 31, q = l >> 5;
    int k = kt * 16 + 8 * q + j;
    int tap = k / CINP;
    int ic  = k - tap * CINP;
    float v = 0.f;
    if (tap < 27 && ic < I && n < O) v = W[(n * I + ic) * 27 + tap];
    Bp[t] = (short)bf16_rne(v);
}

// ---------------- MFMA implicit-GEMM 3x3x3 conv ----------------
// in: bf16 [B][64][64][64][ICG*8]; WG = (b,x,ypair): 2 z-columns, 4 waves.
// wave w: ycol = w>>1, M-tile z base mz = (w&1)*32; N = 32 output channels.
template <int ICG, int KT, bool FINAL>
__global__ __launch_bounds__(256) void mfma_conv_kernel(
    const ushortT* __restrict__ in, const short* __restrict__ Bpack,
    const float* __restrict__ bias, const float* __restrict__ alpha,
    void* __restrict__ outv) {
    constexpr int CIN = ICG * 8;
    __shared__ short lds[12 * ICG * 66 * 8];       // [col12][icg][z66][8ch]
    int wg = blockIdx.x;                           // 2*64*32 = 4096
    int yp = wg & 31, x = (wg >> 5) & 63, b = wg >> 11;
    int y0 = yp * 2;
    int tid = threadIdx.x;

    // ---- stage 12-column halo tile into LDS (layout linear in chunk id) ----
    const int NCH = 12 * ICG * 66;                 // 16B chunks
    for (int cc = tid; cc < NCH; cc += 256) {
        int col = cc / (ICG * 66);
        int rem = cc - col * (ICG * 66);
        int icg = rem / 66;
        int z66 = rem - icg * 66;
        int gx = x + (col >> 2) - 1;               // col = dx*4 + ty
        int gy = y0 + (col & 3) - 1;
        int z  = z66 - 1;
        short8 v = short8{0,0,0,0,0,0,0,0};
        if ((unsigned)gx < 64u && (unsigned)gy < 64u && (unsigned)z < 64u)
            v = *(const short8*)(in + ((size_t)(((b * 64 + gx) * 64 + gy) * 64 + z)) * CIN + icg * 8);
        *(short8*)(lds + cc * 8) = v;
    }
    __syncthreads();

    int l = tid & 63, w = tid >> 6;
    int ycol = w >> 1, mz = (w & 1) * 32;
    int n = l & 31, q = l >> 5;

    float bval = FINAL ? (n < 4 ? bias[n] : 0.f) : bias[n];
    float16 acc;
#pragma unroll
    for (int r = 0; r < 16; ++r) acc[r] = bval;

    const short* bp = Bpack + (size_t)l * 8;
    // lane-invariant part of the A address (in shorts): [.. + z66]*8
    int laneBase = (mz + (l & 31)) * 8;            // z within column (before +dz, +halo offset folded below)
    int ycolOfs  = ycol * (ICG * 66) * 8;

#pragma unroll
    for (int kt = 0; kt < KT; ++kt) {
        short8 bfrag = *(const short8*)(bp + kt * 512);
        int aofs;
        if constexpr (ICG == 1) {
            int tap0 = kt * 2, tap1 = kt * 2 + 1;
            if (tap1 > 26) tap1 = 26;              // B is zero there; any valid addr
            int dx0 = tap0 / 9, r0 = tap0 - dx0 * 9, dy0 = r0 / 3, dz0 = r0 - dy0 * 3;
            int dx1 = tap1 / 9, r1 = tap1 - dx1 * 9, dy1 = r1 / 3, dz1 = r1 - dy1 * 3;
            int c0 = ((dx0 * 4 + dy0) * 66 + dz0) * 8;
            int c1 = ((dx1 * 4 + dy1) * 66 + dz1) * 8;
            aofs = q ? c1 : c0;
        } else {
            int tap = kt >> 1;
            int dx = tap / 9, rr = tap - dx * 9, dy = rr / 3, dz = rr - dy * 3;
            int icg = (kt & 1) * 2 + q;
            aofs = (((dx * 4 + dy) * ICG + icg) * 66 + dz) * 8;
        }
        short8 afrag = *(const short8*)(lds + aofs + ycolOfs + laneBase);
        acc = __builtin_amdgcn_mfma_f32_32x32x16_bf16(afrag, bfrag, acc, 0, 0, 0);
    }

    int ygl = y0 + ycol;
    size_t base = (size_t)(((b * 64 + x) * 64 + ygl) * 64);
    if (FINAL) {
        float* out = (float*)outv;
        if (n < 4) {
#pragma unroll
            for (int r = 0; r < 16; ++r) {
                int z = mz + (r & 3) + 8 * (r >> 2) + 4 * q;
                out[(base + z) * 4 + n] = acc[r];
            }
        }
    } else {
        float a = alpha[0];
        ushortT* out = (ushortT*)outv;
#pragma unroll
        for (int r = 0; r < 16; ++r) {
            int z = mz + (r & 3) + 8 * (r >> 2) + 4 * q;
            float v = acc[r];
            v = v >= 0.f ? v : a * v;
            out[(base + z) * 32 + n] = bf16_rne(v);
        }
    }
}

// ---------------- grid2particles (trilinear gather, fp32 grid) ----------------
__global__ __launch_bounds__(256) void gather_kernel(
    const float* __restrict__ grid, const float* __restrict__ locs,
    float* __restrict__ out) {
    int t = blockIdx.x * blockDim.x + threadIdx.x;
    if (t >= BATCH * NPART) return;
    int b = t >> 15;

    float px = locs[t * 3 + 0] * 64.0f - 0.5f;
    float py = locs[t * 3 + 1] * 64.0f - 0.5f;
    float pz = locs[t * 3 + 2] * 64.0f - 0.5f;
    int ix = (int)floorf(px);
    int iy = (int)floorf(py);
    int iz = (int)floorf(pz);
    float fx = px - (float)ix;
    float fy = py - (float)iy;
    float fz = pz - (float)iz;

    const float* gb = grid + (size_t)b * GD * GD * GD * 4;
    float o0 = 0.f, o1 = 0.f, o2 = 0.f, o3 = 0.f;

#pragma unroll
    for (int dx = 0; dx < 2; ++dx) {
        int x = ix + dx;
        if ((unsigned)x > 63u) continue;
        float wx = dx ? fx : 1.0f - fx;
#pragma unroll
        for (int dy = 0; dy < 2; ++dy) {
            int y = iy + dy;
            if ((unsigned)y > 63u) continue;
            float wy = dy ? fy : 1.0f - fy;
#pragma unroll
            for (int dz = 0; dz < 2; ++dz) {
                int z = iz + dz;
                if ((unsigned)z > 63u) continue;
                float wz = dz ? fz : 1.0f - fz;
                float w = wx * wy * wz;
                const float4 g = *(const float4*)(gb + (size_t)(((x * GD) + y) * GD + z) * 4);
                o0 += w * g.x; o1 += w * g.y; o2 += w * g.z; o3 += w * g.w;
            }
        }
    }
    out[t * 4 + 0] = o0;
    out[t * 4 + 1] = o1;
    out[t * 4 + 2] = o2;
    out[t * 4 + 3] = o3;
}

extern "C" void kernel_launch(void* const* d_in, const int* in_sizes, int n_in,
                              void* d_out, int out_size, void* d_ws, size_t ws_size,
                              hipStream_t stream) {
    const float* locs    = (const float*)d_in[0];
    const float* data    = (const float*)d_in[1];
    const float* density = (const float*)d_in[2];
    const float* W0 = (const float*)d_in[3];
    const float* b0 = (const float*)d_in[4];
    const float* W1 = (const float*)d_in[5];
    const float* b1 = (const float*)d_in[6];
    const float* W2 = (const float*)d_in[7];
    const float* b2 = (const float*)d_in[8];
    const float* W3 = (const float*)d_in[9];
    const float* b3 = (const float*)d_in[10];
    const float* a0 = (const float*)d_in[11];
    const float* a1 = (const float*)d_in[12];
    const float* a2 = (const float*)d_in[13];
    float* out = (float*)d_out;

    char* ws = (char*)d_ws;
    float*  g4   = (float*)(ws);                         // 8 MB fp32 4ch
    ushortT* g8  = (ushortT*)(ws + 8388608);             // 8 MB bf16 8ch
    ushortT* gA  = (ushortT*)(ws + 16777216);            // 33.5 MB bf16 32ch
    ushortT* gB  = (ushortT*)(ws + 50331648);            // 33.5 MB bf16 32ch
    float*  gF   = (float*)(ws + 83886080);              // 8 MB fp32 4ch
    short*  Bp0  = (short*)(ws + 92274688);              // 14*512*2  = 14336 B
    short*  Bp1  = (short*)(ws + 92291072);              // 54*512*2  = 55296 B
    short*  Bp2  = (short*)(ws + 92346368);
    short*  Bp3  = (short*)(ws + 92401664);

    zero_kernel<<<NVOX / 256, 256, 0, stream>>>((float4*)g4, NVOX);

    repack_kernel<<<(14 * 512 + 255) / 256, 256, 0, stream>>>(W0, Bp0, 32,  4,  8, 14);
    repack_kernel<<<(54 * 512 + 255) / 256, 256, 0, stream>>>(W1, Bp1, 32, 32, 32, 54);
    repack_kernel<<<(54 * 512 + 255) / 256, 256, 0, stream>>>(W2, Bp2, 32, 32, 32, 54);
    repack_kernel<<<(54 * 512 + 255) / 256, 256, 0, stream>>>(W3, Bp3,  4, 32, 32, 54);

    splat_kernel<<<(BATCH * NPART) / 256, 256, 0, stream>>>(locs, data, density, g4);
    convert_kernel<<<NVOX / 256, 256, 0, stream>>>((const float4*)g4, (short8*)g8);

    const int CGRID = BATCH * 64 * 32;   // 4096 workgroups
    mfma_conv_kernel< 1, 14, false><<<CGRID, 256, 0, stream>>>(g8, Bp0, b0, a0, gA);
    mfma_conv_kernel< 4, 54, false><<<CGRID, 256, 0, stream>>>(gA, Bp1, b1, a1, gB);
    mfma_conv_kernel< 4, 54, false><<<CGRID, 256, 0, stream>>>(gB, Bp2, b2, a2, gA);
    mfma_conv_kernel< 4, 54, true ><<<CGRID, 256, 0, stream>>>(gA, Bp3, b3, b3, gF);

    gather_kernel<<<(BATCH * NPART) / 256, 256, 0, stream>>>(gF, locs, out);
}